// Round 1
// baseline (145.824 us; speedup 1.0000x reference)
//
#include <hip/hip_runtime.h>
#include <stdint.h>

typedef unsigned short u16;
typedef __attribute__((ext_vector_type(8))) short short8;
typedef __attribute__((ext_vector_type(8))) unsigned short u16x8;
typedef __attribute__((ext_vector_type(4))) float f32x4;

#define MFMA16(a, b, c) __builtin_amdgcn_mfma_f32_16x16x32_bf16((a), (b), (c), 0, 0, 0)

__device__ __forceinline__ u16 f2bf(float f) {
  unsigned int u = __float_as_uint(f);
  u += 0x7FFFu + ((u >> 16) & 1u);
  return (u16)(u >> 16);
}

__device__ __forceinline__ void gload16(const u16* g, u16* lds) {
  __builtin_amdgcn_global_load_lds(
      (const __attribute__((address_space(1))) unsigned int*)g,
      (__attribute__((address_space(3))) unsigned int*)lds, 16, 0, 0);
}

// ---------------- conversions ----------------
__global__ void cvt_bf16_kernel(const float* __restrict__ in, u16* __restrict__ out, int n4) {
  int i = blockIdx.x * blockDim.x + threadIdx.x;
  int stride = gridDim.x * blockDim.x;
  for (; i < n4; i += stride) {
    float4 v = ((const float4*)in)[i];
    ushort4 o;
    o.x = f2bf(v.x); o.y = f2bf(v.y); o.z = f2bf(v.z); o.w = f2bf(v.w);
    ((ushort4*)out)[i] = o;
  }
}

// src is R x C fp32 row-major; dst is C x R bf16 row-major: dst[c][r] = src[r][c]*scale
__global__ void trans_cvt(const float* __restrict__ src, u16* __restrict__ dst,
                          int R, int C, float scale) {
  __shared__ float tile[32][33];
  int bx = blockIdx.x * 32, by = blockIdx.y * 32;
  int tx = threadIdx.x, ty = threadIdx.y;  // block (32,8)
#pragma unroll
  for (int i = 0; i < 4; ++i)
    tile[ty + 8 * i][tx] = src[(size_t)(by + ty + 8 * i) * C + bx + tx];
  __syncthreads();
#pragma unroll
  for (int i = 0; i < 4; ++i)
    dst[(size_t)(bx + ty + 8 * i) * R + by + tx] = f2bf(tile[tx][ty + 8 * i] * scale);
}

// ---------------- GEMM: C[M][N] = A[M][K] * BT[N][K]^T ----------------
// 128x128 tile, BK=32, 256 threads (4 waves 2x2), global_load_lds staging.
template <int OUTF32>
__global__ __launch_bounds__(256) void gemm_bt(const u16* __restrict__ A,
                                               const u16* __restrict__ BT,
                                               void* __restrict__ Cp,
                                               int M, int N, int K) {
  __shared__ __align__(16) u16 As[128 * 32];
  __shared__ __align__(16) u16 Bs[128 * 32];
  const int t = threadIdx.x;
  const int w = t >> 6, l = t & 63, lr = l & 15, lg = l >> 4;
  const int wr = w >> 1, wc = w & 1;
  const int tm = blockIdx.y * 128, tn = blockIdx.x * 128;

  f32x4 acc[4][4];
#pragma unroll
  for (int mi = 0; mi < 4; ++mi)
#pragma unroll
    for (int ni = 0; ni < 4; ++ni) acc[mi][ni] = (f32x4){0.f, 0.f, 0.f, 0.f};

  for (int kt = 0; kt < K; kt += 32) {
#pragma unroll
    for (int p = 0; p < 2; ++p) {
      int ci = p * 256 + t;
      int row = ci >> 2, c8 = ci & 3;
      int ldsoff = (p * 256 + (t & 192)) * 8;  // wave-uniform base chunk
      gload16(A + (size_t)(tm + row) * K + kt + c8 * 8, As + ldsoff);
      gload16(BT + (size_t)(tn + row) * K + kt + c8 * 8, Bs + ldsoff);
    }
    __syncthreads();
    short8 af[4], bf[4];
#pragma unroll
    for (int mi = 0; mi < 4; ++mi)
      af[mi] = *(const short8*)&As[(wr * 64 + mi * 16 + lr) * 32 + lg * 8];
#pragma unroll
    for (int ni = 0; ni < 4; ++ni)
      bf[ni] = *(const short8*)&Bs[(wc * 64 + ni * 16 + lr) * 32 + lg * 8];
#pragma unroll
    for (int mi = 0; mi < 4; ++mi)
#pragma unroll
      for (int ni = 0; ni < 4; ++ni)
        acc[mi][ni] = MFMA16(af[mi], bf[ni], acc[mi][ni]);
    __syncthreads();
  }

  if (OUTF32) {
    float* C = (float*)Cp;
#pragma unroll
    for (int mi = 0; mi < 4; ++mi)
#pragma unroll
      for (int ni = 0; ni < 4; ++ni)
#pragma unroll
        for (int r = 0; r < 4; ++r)
          C[(size_t)(tm + wr * 64 + mi * 16 + lg * 4 + r) * N + tn + wc * 64 + ni * 16 + lr] =
              acc[mi][ni][r];
  } else {
    u16* C = (u16*)Cp;
#pragma unroll
    for (int mi = 0; mi < 4; ++mi)
#pragma unroll
      for (int ni = 0; ni < 4; ++ni)
#pragma unroll
        for (int r = 0; r < 4; ++r)
          C[(size_t)(tm + wr * 64 + mi * 16 + lg * 4 + r) * N + tn + wc * 64 + ni * 16 + lr] =
              f2bf(acc[mi][ni][r]);
  }
}

// ---------------- attention ----------------
// grid (32 qtiles, 32 bh); block 256 = 4 waves, 16 q-rows per wave.
// qb: [b*2048+i][512] (h*64+c), pre-scaled by 1/8 via Wq. kvb: [b*512+j][1024]
// (cols 0..511 = K, 512..1023 = V). aob: [b*2048+i][512].
#define VSTR 264
#define PSTR 40
__global__ __launch_bounds__(256) void attn_kernel(const u16* __restrict__ qb,
                                                   const u16* __restrict__ kvb,
                                                   u16* __restrict__ aob) {
  __shared__ __align__(16) u16 vT[64 * VSTR];      // v^T for current 256-col half
  __shared__ __align__(16) u16 pb[4][16 * PSTR];   // per-wave P transpose window
  const int t = threadIdx.x, w = t >> 6, l = t & 63, lr = l & 15, lg = l >> 4;
  const int qt = blockIdx.x, bh = blockIdx.y, b = bh >> 3, h = bh & 7;
  const int qrow0 = qt * 64 + w * 16;
  const u16* qp = qb + (size_t)(b * 2048 + qrow0) * 512 + h * 64;
  const u16* kp = kvb + (size_t)(b * 512) * 1024 + h * 64;
  const u16* vp = kp + 512;

  short8 qa[2];
#pragma unroll
  for (int s = 0; s < 2; ++s)
    qa[s] = *(const short8*)(qp + (size_t)lr * 512 + s * 32 + lg * 8);

  // stage V^T half 0 (j = 0..255)
  {
    int c = t & 63, jg = t >> 6;
#pragma unroll
    for (int pass = 0; pass < 8; ++pass) {
      int jj0 = pass * 32 + jg * 8;
      u16x8 tmp;
#pragma unroll
      for (int i = 0; i < 8; ++i) tmp[i] = vp[(size_t)(jj0 + i) * 1024 + c];
      *(u16x8*)&vT[c * VSTR + jj0] = tmp;
    }
  }

  // scores: full 512 cols in registers (q pre-scaled by 1/8)
  f32x4 sc[32];
#pragma unroll
  for (int jt = 0; jt < 32; ++jt) {
    const u16* kr = kp + (size_t)(jt * 16 + lr) * 1024 + lg * 8;
    short8 k0 = *(const short8*)kr;
    short8 k1 = *(const short8*)(kr + 32);
    f32x4 a = (f32x4){0.f, 0.f, 0.f, 0.f};
    a = MFMA16(qa[0], k0, a);
    a = MFMA16(qa[1], k1, a);
    sc[jt] = a;
  }

  // softmax over 512 (rows = lg*4 + r; reduce across 16 lanes of same lg)
  float invs[4];
#pragma unroll
  for (int r = 0; r < 4; ++r) {
    float m = sc[0][r];
#pragma unroll
    for (int jt = 1; jt < 32; ++jt) m = fmaxf(m, sc[jt][r]);
    m = fmaxf(m, __shfl_xor(m, 1));
    m = fmaxf(m, __shfl_xor(m, 2));
    m = fmaxf(m, __shfl_xor(m, 4));
    m = fmaxf(m, __shfl_xor(m, 8));
    float s = 0.f;
#pragma unroll
    for (int jt = 0; jt < 32; ++jt) {
      float e = __expf(sc[jt][r] - m);
      sc[jt][r] = e;
      s += e;
    }
    s += __shfl_xor(s, 1);
    s += __shfl_xor(s, 2);
    s += __shfl_xor(s, 4);
    s += __shfl_xor(s, 8);
    invs[r] = 1.f / s;
  }

  __syncthreads();  // V^T half 0 staged

  f32x4 oac[4];
#pragma unroll
  for (int ct = 0; ct < 4; ++ct) oac[ct] = (f32x4){0.f, 0.f, 0.f, 0.f};

  u16* pw = pb[w];
#pragma unroll
  for (int half = 0; half < 2; ++half) {
    if (half == 1) {
      __syncthreads();  // all PV reads of half 0 done
      int c = t & 63, jg = t >> 6;
#pragma unroll
      for (int pass = 0; pass < 8; ++pass) {
        int jj0 = pass * 32 + jg * 8;
        u16x8 tmp;
#pragma unroll
        for (int i = 0; i < 8; ++i) tmp[i] = vp[(size_t)(256 + jj0 + i) * 1024 + c];
        *(u16x8*)&vT[c * VSTR + jj0] = tmp;
      }
      __syncthreads();
    }
#pragma unroll
    for (int ks = 0; ks < 8; ++ks) {
      // write P window (32 cols) to per-wave LDS, transposing frag layout
#pragma unroll
      for (int dj = 0; dj < 2; ++dj) {
        int jt = half * 16 + ks * 2 + dj;
#pragma unroll
        for (int r = 0; r < 4; ++r)
          pw[(lg * 4 + r) * PSTR + dj * 16 + lr] = f2bf(sc[jt][r]);
      }
      short8 pa = *(const short8*)&pw[lr * PSTR + lg * 8];
#pragma unroll
      for (int ct = 0; ct < 4; ++ct) {
        short8 vf = *(const short8*)&vT[(ct * 16 + lr) * VSTR + ks * 32 + lg * 8];
        oac[ct] = MFMA16(pa, vf, oac[ct]);
      }
    }
  }

  // epilogue: divide by row sums, store merged-head bf16
  u16* op = aob + (size_t)(b * 2048 + qrow0) * 512 + h * 64;
#pragma unroll
  for (int ct = 0; ct < 4; ++ct)
#pragma unroll
    for (int r = 0; r < 4; ++r)
      op[(size_t)(lg * 4 + r) * 512 + ct * 16 + lr] = f2bf(oac[ct][r] * invs[r]);
}

// ---------------- launch ----------------
extern "C" void kernel_launch(void* const* d_in, const int* in_sizes, int n_in,
                              void* d_out, int out_size, void* d_ws, size_t ws_size,
                              hipStream_t stream) {
  const float* x  = (const float*)d_in[0];  // [4,2048,1024]
  const float* cx = (const float*)d_in[1];  // [4,512,768]
  const float* Wq = (const float*)d_in[2];  // [1024,512]
  const float* Wk = (const float*)d_in[3];  // [768,512]
  const float* Wv = (const float*)d_in[4];  // [768,512]
  const float* Wo = (const float*)d_in[5];  // [512,1024]
  float* out = (float*)d_out;               // [4,2048,1024]

  char* p = (char*)d_ws;
  u16* xb   = (u16*)p; p += (size_t)8388608 * 2;   // x bf16
  u16* cb   = (u16*)p; p += (size_t)1572864 * 2;   // context bf16
  u16* wqT  = (u16*)p; p += (size_t)524288 * 2;    // Wq^T * 0.125   [512][1024]
  u16* wkvT = (u16*)p; p += (size_t)786432 * 2;    // [Wk^T; Wv^T]   [1024][768]
  u16* woT  = (u16*)p; p += (size_t)524288 * 2;    // Wo^T           [1024][512]
  u16* qb   = (u16*)p; p += (size_t)4194304 * 2;   // q              [8192][512]
  u16* kvb  = (u16*)p; p += (size_t)2097152 * 2;   // k|v            [2048][1024]
  u16* aob  = (u16*)p; p += (size_t)4194304 * 2;   // attn out       [8192][512]

  cvt_bf16_kernel<<<2048, 256, 0, stream>>>(x, xb, 8388608 / 4);
  cvt_bf16_kernel<<<1024, 256, 0, stream>>>(cx, cb, 1572864 / 4);
  trans_cvt<<<dim3(512 / 32, 1024 / 32), dim3(32, 8), 0, stream>>>(Wq, wqT, 1024, 512, 0.125f);
  trans_cvt<<<dim3(512 / 32, 768 / 32), dim3(32, 8), 0, stream>>>(Wk, wkvT, 768, 512, 1.0f);
  trans_cvt<<<dim3(512 / 32, 768 / 32), dim3(32, 8), 0, stream>>>(Wv, wkvT + (size_t)512 * 768, 768, 512, 1.0f);
  trans_cvt<<<dim3(1024 / 32, 512 / 32), dim3(32, 8), 0, stream>>>(Wo, woT, 512, 1024, 1.0f);

  gemm_bt<0><<<dim3(4, 64), 256, 0, stream>>>(xb, wqT, qb, 8192, 512, 1024);
  gemm_bt<0><<<dim3(8, 16), 256, 0, stream>>>(cb, wkvT, kvb, 2048, 1024, 768);
  attn_kernel<<<dim3(32, 32), 256, 0, stream>>>(qb, kvb, aob);
  gemm_bt<1><<<dim3(8, 64), 256, 0, stream>>>(aob, woT, out, 8192, 1024, 512);
}